// Round 3
// baseline (429.504 us; speedup 1.0000x reference)
//
#include <hip/hip_runtime.h>
#include <math.h>

// Problem constants (match reference)
constexpr int Sx    = 2048;
constexpr int Dx    = 512;
constexpr int Hx    = 8;
constexpr int QDx   = 256;
constexpr int HALFx = 128;
constexpr int PKx   = 256;
constexpr int Kx    = 16;
constexpr int HQx   = Hx * QDx;   // 2048
constexpr int Rx    = Sx * Hx;    // 16384 (s,h) rows
constexpr int Ox    = 512;

// ---------------------------------------------------------------------------
// K0: l2-normalize the product keys (2 x 256 rows of 128)
// ---------------------------------------------------------------------------
__global__ __launch_bounds__(64) void knorm_kernel(
    const float* __restrict__ k0, const float* __restrict__ k1,
    float* __restrict__ k0n, float* __restrict__ k1n)
{
    const int row = blockIdx.x;              // 0..511
    const float* src = (row < PKx) ? (k0 + (size_t)row * HALFx)
                                   : (k1 + (size_t)(row - PKx) * HALFx);
    float* dst = (row < PKx) ? (k0n + (size_t)row * HALFx)
                             : (k1n + (size_t)(row - PKx) * HALFx);
    const int t = threadIdx.x;               // 0..63
    float a = src[t];
    float b = src[t + 64];
    float ss = a * a + b * b;
#pragma unroll
    for (int off = 32; off; off >>= 1) ss += __shfl_xor(ss, off);
    float n = sqrtf(ss);
    n = fmaxf(n, 1e-12f);
    dst[t]      = a / n;
    dst[t + 64] = b / n;
}

// ---------------------------------------------------------------------------
// K1: shared f32 GEMM template: C(M x N) = A(M x K) @ B(N x K)^T [+ bias]
// BM=128, BN=64, BK=32, 256 threads, per-thread 8x4 tile.
// float4 global loads + register prefetch of next K-tile (issue-early),
// staging writes 4x b32 (<=4-way, negligible vs 32 fma/k-step compute).
// ---------------------------------------------------------------------------
__global__ __launch_bounds__(256) void gemm128_kernel(
    const float* __restrict__ A, int lda,
    const float* __restrict__ B, int ldb,
    const float* __restrict__ bias,
    float* __restrict__ C, int ldc, int K)
{
    constexpr int BM = 128, BN = 64, BK = 32;
    constexpr int ASTR = BM + 4;   // 132 floats (16B-aligned rows)
    constexpr int BSTR = BN + 4;   // 68
    __shared__ __align__(16) float As[BK * ASTR];
    __shared__ __align__(16) float Bs[BK * BSTR];
    const int tid = threadIdx.x;
    const int bm = blockIdx.y * BM;
    const int bn = blockIdx.x * BN;

    // staging: A-tile 128x32 = 1024 quads (4/thread), B-tile 64x32 = 512 (2/thread)
    const int sq = tid & 7;          // k-quad within row (k = sq*4..sq*4+3)
    const int sr = tid >> 3;         // base row 0..31
    // compute mapping: 16x16 thread grid
    const int m0 = (tid >> 4) * 8;   // 8 rows
    const int n0 = (tid & 15) * 4;   // 4 cols

    float4 pa[4], pb[2];
#pragma unroll
    for (int i = 0; i < 4; ++i)
        pa[i] = *(const float4*)&A[(size_t)(bm + sr + i * 32) * lda + sq * 4];
#pragma unroll
    for (int i = 0; i < 2; ++i)
        pb[i] = *(const float4*)&B[(size_t)(bn + sr + i * 32) * ldb + sq * 4];

    float acc[8][4] = {{0.f}};
    const int niter = K / BK;
    for (int it = 0; it < niter; ++it) {
        __syncthreads();   // previous compute done before overwrite (no-op at it=0)
#pragma unroll
        for (int i = 0; i < 4; ++i) {
            const float v[4] = {pa[i].x, pa[i].y, pa[i].z, pa[i].w};
#pragma unroll
            for (int j = 0; j < 4; ++j)
                As[(sq * 4 + j) * ASTR + sr + i * 32] = v[j];
        }
#pragma unroll
        for (int i = 0; i < 2; ++i) {
            const float v[4] = {pb[i].x, pb[i].y, pb[i].z, pb[i].w};
#pragma unroll
            for (int j = 0; j < 4; ++j)
                Bs[(sq * 4 + j) * BSTR + sr + i * 32] = v[j];
        }
        __syncthreads();
        // prefetch next K-tile into regs (overlaps with compute below)
        if (it + 1 < niter) {
            const int ko = (it + 1) * BK;
#pragma unroll
            for (int i = 0; i < 4; ++i)
                pa[i] = *(const float4*)&A[(size_t)(bm + sr + i * 32) * lda + ko + sq * 4];
#pragma unroll
            for (int i = 0; i < 2; ++i)
                pb[i] = *(const float4*)&B[(size_t)(bn + sr + i * 32) * ldb + ko + sq * 4];
        }
#pragma unroll
        for (int k = 0; k < BK; ++k) {
            float af[8], bf[4];
            *(float4*)&af[0] = *(const float4*)&As[k * ASTR + m0];
            *(float4*)&af[4] = *(const float4*)&As[k * ASTR + m0 + 4];
            *(float4*)&bf[0] = *(const float4*)&Bs[k * BSTR + n0];
#pragma unroll
            for (int i = 0; i < 8; ++i)
#pragma unroll
                for (int j = 0; j < 4; ++j)
                    acc[i][j] = fmaf(af[i], bf[j], acc[i][j]);
        }
    }
    // epilogue
    float4 bv = make_float4(0.f, 0.f, 0.f, 0.f);
    if (bias) bv = *(const float4*)&bias[bn + n0];
#pragma unroll
    for (int i = 0; i < 8; ++i) {
        float4 o;
        o.x = acc[i][0] + bv.x;
        o.y = acc[i][1] + bv.y;
        o.z = acc[i][2] + bv.z;
        o.w = acc[i][3] + bv.w;
        *(float4*)&C[(size_t)(bm + m0 + i) * ldc + bn + n0] = o;
    }
}

// ---------------------------------------------------------------------------
// K2: LayerNorm(QD=256) + split-half l2norm, in place. One wave per (s,h).
// ---------------------------------------------------------------------------
__global__ __launch_bounds__(64) void ln_kernel(
    float* __restrict__ q, const float* __restrict__ g,
    const float* __restrict__ b)
{
    const int r = blockIdx.x;                 // 0..16383
    float* row = q + (size_t)r * QDx;
    const int t = threadIdx.x;                // 0..63
    float v0 = row[t], v1 = row[t + 64], v2 = row[t + 128], v3 = row[t + 192];
    float sum = v0 + v1 + v2 + v3;
#pragma unroll
    for (int off = 32; off; off >>= 1) sum += __shfl_xor(sum, off);
    const float mu = sum * (1.f / 256.f);
    float d0 = v0 - mu, d1 = v1 - mu, d2 = v2 - mu, d3 = v3 - mu;
    float ss = d0 * d0 + d1 * d1 + d2 * d2 + d3 * d3;
#pragma unroll
    for (int off = 32; off; off >>= 1) ss += __shfl_xor(ss, off);
    const float var = ss * (1.f / 256.f);
    const float inv = 1.0f / sqrtf(var + 1e-5f);
    v0 = d0 * inv * g[t]       + b[t];
    v1 = d1 * inv * g[t + 64]  + b[t + 64];
    v2 = d2 * inv * g[t + 128] + b[t + 128];
    v3 = d3 * inv * g[t + 192] + b[t + 192];
    float s0 = v0 * v0 + v1 * v1;
#pragma unroll
    for (int off = 32; off; off >>= 1) s0 += __shfl_xor(s0, off);
    float n0 = fmaxf(sqrtf(s0), 1e-12f);
    float s1 = v2 * v2 + v3 * v3;
#pragma unroll
    for (int off = 32; off; off >>= 1) s1 += __shfl_xor(s1, off);
    float n1 = fmaxf(sqrtf(s1), 1e-12f);
    row[t]       = v0 / n0;
    row[t + 64]  = v1 / n0;
    row[t + 128] = v2 / n1;
    row[t + 192] = v3 / n1;
}

// ---------------------------------------------------------------------------
// K4: per (s,h) row: top-16(s0), top-16(s1), 256 combos, top-16, softmax.
// Ballot-based radix threshold selection (round-1 win, unchanged).
// ---------------------------------------------------------------------------
__device__ __forceinline__ unsigned fkey(float f) {
    unsigned u = __float_as_uint(f);
    return u ^ ((u & 0x80000000u) ? 0xFFFFFFFFu : 0x80000000u);
}

__device__ __forceinline__ void extract16(
    const float v[4], const unsigned u[4], unsigned T, int lane,
    unsigned long long lmask, float* outv, int* outi)
{
    unsigned long long mg[4];
    int gt_total = 0;
#pragma unroll
    for (int j = 0; j < 4; ++j) {
        mg[j] = __ballot(u[j] > T);
        gt_total += __popcll(mg[j]);
    }
    int bg = 0, be = gt_total;
#pragma unroll
    for (int j = 0; j < 4; ++j) {
        unsigned long long me = __ballot(u[j] == T);
        int idx = lane + 64 * j;
        if (u[j] > T) {
            int pg = bg + __popcll(mg[j] & lmask);
            outv[pg] = v[j]; outi[pg] = idx;
        } else if (u[j] == T) {
            int pe = be + __popcll(me & lmask);
            if (pe < 16) { outv[pe] = v[j]; outi[pe] = idx; }
        }
        bg += __popcll(mg[j]);
        be += __popcll(me);
    }
}

__global__ __launch_bounds__(64) void topk_kernel(
    const float* __restrict__ s0g, const float* __restrict__ s1g,
    int* __restrict__ fib, float* __restrict__ wb)
{
    __shared__ float sc0[Kx], sc1[Kx], fsv[Kx];
    __shared__ int ix0[Kx], ix1[Kx], fid[Kx];
    const int r = blockIdx.x;
    const int lane = threadIdx.x;
    const unsigned long long lmask = (1ull << lane) - 1ull;

    float v0[4], v1[4];
    unsigned u0[4], u1[4];
#pragma unroll
    for (int j = 0; j < 4; ++j) {
        v0[j] = s0g[(size_t)r * PKx + lane + 64 * j];
        v1[j] = s1g[(size_t)r * PKx + lane + 64 * j];
        u0[j] = fkey(v0[j]);
        u1[j] = fkey(v1[j]);
    }

    unsigned T0 = 0, T1 = 0;
    for (int bit = 31; bit >= 0; --bit) {
        const unsigned c0 = T0 | (1u << bit);
        const unsigned c1 = T1 | (1u << bit);
        int n0 = 0, n1 = 0;
#pragma unroll
        for (int j = 0; j < 4; ++j) {
            n0 += __popcll(__ballot(u0[j] >= c0));
            n1 += __popcll(__ballot(u1[j] >= c1));
        }
        if (n0 >= Kx) T0 = c0;
        if (n1 >= Kx) T1 = c1;
    }
    extract16(v0, u0, T0, lane, lmask, sc0, ix0);
    extract16(v1, u1, T1, lane, lmask, sc1, ix1);
    __syncthreads();

    float cv[4];
    unsigned cu[4];
    int ci[4];
#pragma unroll
    for (int j = 0; j < 4; ++j) {
        int p = lane + 64 * j;
        cv[j] = sc0[p >> 4] + sc1[p & 15];
        cu[j] = fkey(cv[j]);
        ci[j] = ix0[p >> 4] + ix1[p & 15];  // reference ADDS the two indices
    }
    unsigned T2 = 0;
    for (int bit = 31; bit >= 0; --bit) {
        const unsigned c2 = T2 | (1u << bit);
        int n2 = 0;
#pragma unroll
        for (int j = 0; j < 4; ++j) n2 += __popcll(__ballot(cu[j] >= c2));
        if (n2 >= Kx) T2 = c2;
    }
    {
        unsigned long long mg[4];
        int gt_total = 0;
#pragma unroll
        for (int j = 0; j < 4; ++j) {
            mg[j] = __ballot(cu[j] > T2);
            gt_total += __popcll(mg[j]);
        }
        int bg = 0, be = gt_total;
#pragma unroll
        for (int j = 0; j < 4; ++j) {
            unsigned long long me = __ballot(cu[j] == T2);
            if (cu[j] > T2) {
                int pg = bg + __popcll(mg[j] & lmask);
                fsv[pg] = cv[j]; fid[pg] = ci[j];
            } else if (cu[j] == T2) {
                int pe = be + __popcll(me & lmask);
                if (pe < 16) { fsv[pe] = cv[j]; fid[pe] = ci[j]; }
            }
            bg += __popcll(mg[j]);
            be += __popcll(me);
        }
    }
    __syncthreads();

    float f = fsv[lane & 15];
    float mx = f;
#pragma unroll
    for (int off = 8; off; off >>= 1) mx = fmaxf(mx, __shfl_xor(mx, off, 16));
    float e = expf(f - mx);
    float sum = e;
#pragma unroll
    for (int off = 8; off; off >>= 1) sum += __shfl_xor(sum, off, 16);
    if (lane < Kx) {
        fib[(size_t)r * Kx + lane] = fid[lane];
        wb[(size_t)r * Kx + lane]  = e / sum;
    }
}

// ---------------------------------------------------------------------------
// K5: expert evaluation. One block (4 waves) per s.
// phase1: hidden row hoisted to regs (8/lane); 32 serial p per wave.
// phase2: waves split the 128 p (32 each), per-lane 8-wide out chunk,
//         LDS partial reduce at the end.
// ---------------------------------------------------------------------------
__global__ __launch_bounds__(256) void expert_kernel(
    const float* __restrict__ hidden, const float* __restrict__ down,
    const float* __restrict__ up, const int* __restrict__ fib,
    const float* __restrict__ wb, float* __restrict__ out)
{
    __shared__ float aw[Hx * Kx];
    __shared__ int fis[Hx * Kx];
    __shared__ float part[4][Ox];
    const int s = blockIdx.x;
    const int tid = threadIdx.x;
    const int wv = tid >> 6;
    const int lane = tid & 63;
    if (tid < Hx * Kx) fis[tid] = fib[(size_t)s * (Hx * Kx) + tid];
    float h8[8];
#pragma unroll
    for (int i = 0; i < 8; ++i) h8[i] = hidden[(size_t)s * Dx + lane + 64 * i];
    __syncthreads();
    for (int p = wv; p < Hx * Kx; p += 4) {
        const float* dr = down + (size_t)fis[p] * Dx;
        float acc = 0.f;
#pragma unroll
        for (int i = 0; i < 8; ++i)
            acc = fmaf(h8[i], dr[lane + 64 * i], acc);
#pragma unroll
        for (int off = 32; off; off >>= 1) acc += __shfl_xor(acc, off);
        if (lane == 0) {
            float x = acc;
            float act = 0.5f * x * (1.f + erff(x * 0.70710678118654752f));
            aw[p] = act * wb[(size_t)s * (Hx * Kx) + p];
        }
    }
    __syncthreads();
    float a8[8] = {0.f, 0.f, 0.f, 0.f, 0.f, 0.f, 0.f, 0.f};
    const int o0 = lane * 8;
    for (int p = wv * 32; p < wv * 32 + 32; ++p) {
        const float a = aw[p];
        const float* ur = up + (size_t)fis[p] * Ox + o0;
        float4 u0 = *(const float4*)ur;
        float4 u1 = *(const float4*)(ur + 4);
        a8[0] = fmaf(a, u0.x, a8[0]); a8[1] = fmaf(a, u0.y, a8[1]);
        a8[2] = fmaf(a, u0.z, a8[2]); a8[3] = fmaf(a, u0.w, a8[3]);
        a8[4] = fmaf(a, u1.x, a8[4]); a8[5] = fmaf(a, u1.y, a8[5]);
        a8[6] = fmaf(a, u1.z, a8[6]); a8[7] = fmaf(a, u1.w, a8[7]);
    }
    *(float4*)&part[wv][o0]     = make_float4(a8[0], a8[1], a8[2], a8[3]);
    *(float4*)&part[wv][o0 + 4] = make_float4(a8[4], a8[5], a8[6], a8[7]);
    __syncthreads();
    float r0 = part[0][tid] + part[1][tid] + part[2][tid] + part[3][tid];
    float r1 = part[0][tid + 256] + part[1][tid + 256]
             + part[2][tid + 256] + part[3][tid + 256];
    out[(size_t)s * Ox + tid]       = r0;
    out[(size_t)s * Ox + tid + 256] = r1;
}

// ---------------------------------------------------------------------------
extern "C" void kernel_launch(void* const* d_in, const int* in_sizes, int n_in,
                              void* d_out, int out_size, void* d_ws, size_t ws_size,
                              hipStream_t stream)
{
    const float* hidden = (const float*)d_in[0];
    const float* Wq     = (const float*)d_in[1];
    const float* bq     = (const float*)d_in[2];
    const float* ln_g   = (const float*)d_in[3];
    const float* ln_b   = (const float*)d_in[4];
    const float* keys0  = (const float*)d_in[5];
    const float* keys1  = (const float*)d_in[6];
    const float* edown  = (const float*)d_in[7];
    const float* eup    = (const float*)d_in[8];
    float* out = (float*)d_out;

    float* ws  = (float*)d_ws;
    float* q   = ws;                                  // Sx*HQx
    float* k0n = q + (size_t)Sx * HQx;                // PKx*HALFx
    float* k1n = k0n + (size_t)PKx * HALFx;
    float* s0  = k1n + (size_t)PKx * HALFx;           // Rx*PKx
    float* s1  = s0 + (size_t)Rx * PKx;
    float* wb  = s1 + (size_t)Rx * PKx;               // Rx*Kx
    int*   fib = (int*)(wb + (size_t)Rx * Kx);

    hipLaunchKernelGGL(knorm_kernel, dim3(2 * PKx), dim3(64), 0, stream,
                       keys0, keys1, k0n, k1n);
    // qproj: C(2048x2048) = hidden(2048x512) @ Wq^T + bq
    hipLaunchKernelGGL(gemm128_kernel, dim3(HQx / 64, Sx / 128), dim3(256), 0, stream,
                       hidden, Dx, Wq, Dx, bq, q, HQx, Dx);
    hipLaunchKernelGGL(ln_kernel, dim3(Rx), dim3(64), 0, stream, q, ln_g, ln_b);
    // scores: s_half(16384x256) = qn_half(16384x128) @ keys_half^T
    hipLaunchKernelGGL(gemm128_kernel, dim3(PKx / 64, Rx / 128), dim3(256), 0, stream,
                       q, QDx, k0n, HALFx, (const float*)nullptr, s0, PKx, HALFx);
    hipLaunchKernelGGL(gemm128_kernel, dim3(PKx / 64, Rx / 128), dim3(256), 0, stream,
                       q + HALFx, QDx, k1n, HALFx, (const float*)nullptr, s1, PKx, HALFx);
    hipLaunchKernelGGL(topk_kernel, dim3(Rx), dim3(64), 0, stream, s0, s1, fib, wb);
    hipLaunchKernelGGL(expert_kernel, dim3(Sx), dim3(256), 0, stream,
                       hidden, edown, eup, fib, wb, out);
}

// Round 6
// 414.403 us; speedup vs baseline: 1.0364x; 1.0364x over previous
//
#include <hip/hip_runtime.h>
#include <math.h>

// Problem constants (match reference)
constexpr int Sx    = 2048;
constexpr int Dx    = 512;
constexpr int Hx    = 8;
constexpr int QDx   = 256;
constexpr int HALFx = 128;
constexpr int PKx   = 256;
constexpr int Kx    = 16;
constexpr int HQx   = Hx * QDx;   // 2048
constexpr int Rx    = Sx * Hx;    // 16384 (s,h) rows
constexpr int Ox    = 512;
constexpr int NEXP  = 511;        // ci = ix0+ix1 <= 510 -> only rows 0..510 used

// ---- bf16 helpers (RNE) ---------------------------------------------------
__device__ __forceinline__ unsigned short f2bf(float x) {
    unsigned u = __float_as_uint(x);
    unsigned r = (u + 0x7FFFu + ((u >> 16) & 1u)) >> 16;
    return (unsigned short)r;
}
__device__ __forceinline__ float bf2f(unsigned short h) {
    return __uint_as_float(((unsigned)h) << 16);
}

// ---------------------------------------------------------------------------
// K0: l2-normalize the product keys (2 x 256 rows of 128), f32 out.
// ---------------------------------------------------------------------------
__global__ __launch_bounds__(64) void knorm_kernel(
    const float* __restrict__ k0, const float* __restrict__ k1,
    float* __restrict__ k0n, float* __restrict__ k1n)
{
    const int row = blockIdx.x;              // 0..511
    const float* src = (row < PKx) ? (k0 + (size_t)row * HALFx)
                                   : (k1 + (size_t)(row - PKx) * HALFx);
    float* dst = (row < PKx) ? (k0n + (size_t)row * HALFx)
                             : (k1n + (size_t)(row - PKx) * HALFx);
    const int t = threadIdx.x;               // 0..63
    float a = src[t];
    float b = src[t + 64];
    float ss = a * a + b * b;
#pragma unroll
    for (int off = 32; off; off >>= 1) ss += __shfl_xor(ss, off);
    float n = fmaxf(sqrtf(ss), 1e-12f);
    dst[t]      = a / n;
    dst[t + 64] = b / n;
}

// ---------------------------------------------------------------------------
// Kc: convert first NEXP rows of an f32 table (row length 512) to bf16.
// ---------------------------------------------------------------------------
__global__ __launch_bounds__(256) void conv_kernel(
    const float* __restrict__ src, unsigned short* __restrict__ dst, int n4)
{
    int i = blockIdx.x * 256 + threadIdx.x;
    if (i >= n4) return;
    float4 v = ((const float4*)src)[i];
    ((ushort4*)dst)[i] = make_ushort4(f2bf(v.x), f2bf(v.y), f2bf(v.z), f2bf(v.w));
}

// ---------------------------------------------------------------------------
// K1: f32 GEMM template (round-2, known-pass): C(MxN) = A(MxK) @ B(NxK)^T
// BM=128, BN=64, BK=32, 256 threads, per-thread 8x4 tile, reg prefetch.
// ---------------------------------------------------------------------------
__global__ __launch_bounds__(256) void gemm128_kernel(
    const float* __restrict__ A, int lda,
    const float* __restrict__ B, int ldb,
    const float* __restrict__ bias,
    float* __restrict__ C, int ldc, int K)
{
    constexpr int BM = 128, BN = 64, BK = 32;
    constexpr int ASTR = BM + 4;   // 132
    constexpr int BSTR = BN + 4;   // 68
    __shared__ __align__(16) float As[BK * ASTR];
    __shared__ __align__(16) float Bs[BK * BSTR];
    const int tid = threadIdx.x;
    const int bm = blockIdx.y * BM;
    const int bn = blockIdx.x * BN;

    const int sq = tid & 7;          // k-quad (k = sq*4..sq*4+3)
    const int sr = tid >> 3;         // base row 0..31
    const int m0 = (tid >> 4) * 8;   // 8 rows
    const int n0 = (tid & 15) * 4;   // 4 cols

    float4 pa[4], pb[2];
#pragma unroll
    for (int i = 0; i < 4; ++i)
        pa[i] = *(const float4*)&A[(size_t)(bm + sr + i * 32) * lda + sq * 4];
#pragma unroll
    for (int i = 0; i < 2; ++i)
        pb[i] = *(const float4*)&B[(size_t)(bn + sr + i * 32) * ldb + sq * 4];

    float acc[8][4] = {{0.f}};
    const int niter = K / BK;
    for (int it = 0; it < niter; ++it) {
        __syncthreads();
#pragma unroll
        for (int i = 0; i < 4; ++i) {
            const float v[4] = {pa[i].x, pa[i].y, pa[i].z, pa[i].w};
#pragma unroll
            for (int j = 0; j < 4; ++j)
                As[(sq * 4 + j) * ASTR + sr + i * 32] = v[j];
        }
#pragma unroll
        for (int i = 0; i < 2; ++i) {
            const float v[4] = {pb[i].x, pb[i].y, pb[i].z, pb[i].w};
#pragma unroll
            for (int j = 0; j < 4; ++j)
                Bs[(sq * 4 + j) * BSTR + sr + i * 32] = v[j];
        }
        __syncthreads();
        if (it + 1 < niter) {
            const int ko = (it + 1) * BK;
#pragma unroll
            for (int i = 0; i < 4; ++i)
                pa[i] = *(const float4*)&A[(size_t)(bm + sr + i * 32) * lda + ko + sq * 4];
#pragma unroll
            for (int i = 0; i < 2; ++i)
                pb[i] = *(const float4*)&B[(size_t)(bn + sr + i * 32) * ldb + ko + sq * 4];
        }
#pragma unroll
        for (int k = 0; k < BK; ++k) {
            float af[8], bf[4];
            *(float4*)&af[0] = *(const float4*)&As[k * ASTR + m0];
            *(float4*)&af[4] = *(const float4*)&As[k * ASTR + m0 + 4];
            *(float4*)&bf[0] = *(const float4*)&Bs[k * BSTR + n0];
#pragma unroll
            for (int i = 0; i < 8; ++i)
#pragma unroll
                for (int j = 0; j < 4; ++j)
                    acc[i][j] = fmaf(af[i], bf[j], acc[i][j]);
        }
    }
    float4 bv = make_float4(0.f, 0.f, 0.f, 0.f);
    if (bias) bv = *(const float4*)&bias[bn + n0];
#pragma unroll
    for (int i = 0; i < 8; ++i) {
        float4 o;
        o.x = acc[i][0] + bv.x;
        o.y = acc[i][1] + bv.y;
        o.z = acc[i][2] + bv.z;
        o.w = acc[i][3] + bv.w;
        *(float4*)&C[(size_t)(bm + m0 + i) * ldc + bn + n0] = o;
    }
}

// ---------------------------------------------------------------------------
// K2: LayerNorm(256) + split-half l2norm, in place. 4 rows per 256-thr block.
// ---------------------------------------------------------------------------
__global__ __launch_bounds__(256) void ln_kernel(
    float* __restrict__ q, const float* __restrict__ g,
    const float* __restrict__ b)
{
    const int r = blockIdx.x * 4 + (threadIdx.x >> 6);   // 0..16383
    float* row = q + (size_t)r * QDx;
    const int t = threadIdx.x & 63;
    float v0 = row[t], v1 = row[t + 64], v2 = row[t + 128], v3 = row[t + 192];
    float sum = v0 + v1 + v2 + v3;
#pragma unroll
    for (int off = 32; off; off >>= 1) sum += __shfl_xor(sum, off);
    const float mu = sum * (1.f / 256.f);
    float d0 = v0 - mu, d1 = v1 - mu, d2 = v2 - mu, d3 = v3 - mu;
    float ss = d0 * d0 + d1 * d1 + d2 * d2 + d3 * d3;
#pragma unroll
    for (int off = 32; off; off >>= 1) ss += __shfl_xor(ss, off);
    const float var = ss * (1.f / 256.f);
    const float inv = 1.0f / sqrtf(var + 1e-5f);
    v0 = d0 * inv * g[t]       + b[t];
    v1 = d1 * inv * g[t + 64]  + b[t + 64];
    v2 = d2 * inv * g[t + 128] + b[t + 128];
    v3 = d3 * inv * g[t + 192] + b[t + 192];
    float s0 = v0 * v0 + v1 * v1;
#pragma unroll
    for (int off = 32; off; off >>= 1) s0 += __shfl_xor(s0, off);
    float n0 = fmaxf(sqrtf(s0), 1e-12f);
    float s1 = v2 * v2 + v3 * v3;
#pragma unroll
    for (int off = 32; off; off >>= 1) s1 += __shfl_xor(s1, off);
    float n1 = fmaxf(sqrtf(s1), 1e-12f);
    row[t]       = v0 / n0;
    row[t + 64]  = v1 / n0;
    row[t + 128] = v2 / n1;
    row[t + 192] = v3 / n1;
}

// ---------------------------------------------------------------------------
// K4: per (s,h) row top-16 x3 + softmax. Ballot radix select.
// 4 rows per 256-thread block (one row per wave).
// ---------------------------------------------------------------------------
__device__ __forceinline__ unsigned fkey(float f) {
    unsigned u = __float_as_uint(f);
    return u ^ ((u & 0x80000000u) ? 0xFFFFFFFFu : 0x80000000u);
}

__device__ __forceinline__ void extract16(
    const float v[4], const unsigned u[4], unsigned T, int lane,
    unsigned long long lmask, float* outv, int* outi)
{
    unsigned long long mg[4];
    int gt_total = 0;
#pragma unroll
    for (int j = 0; j < 4; ++j) {
        mg[j] = __ballot(u[j] > T);
        gt_total += __popcll(mg[j]);
    }
    int bg = 0, be = gt_total;
#pragma unroll
    for (int j = 0; j < 4; ++j) {
        unsigned long long me = __ballot(u[j] == T);
        int idx = lane + 64 * j;
        if (u[j] > T) {
            int pg = bg + __popcll(mg[j] & lmask);
            outv[pg] = v[j]; outi[pg] = idx;
        } else if (u[j] == T) {
            int pe = be + __popcll(me & lmask);
            if (pe < 16) { outv[pe] = v[j]; outi[pe] = idx; }
        }
        bg += __popcll(mg[j]);
        be += __popcll(me);
    }
}

__global__ __launch_bounds__(256) void topk_kernel(
    const float* __restrict__ s0g, const float* __restrict__ s1g,
    int* __restrict__ fib, float* __restrict__ wb)
{
    __shared__ float sc0[4][Kx], sc1[4][Kx], fsv[4][Kx];
    __shared__ int ix0[4][Kx], ix1[4][Kx], fid[4][Kx];
    const int w = threadIdx.x >> 6;
    const int r = blockIdx.x * 4 + w;
    const int lane = threadIdx.x & 63;
    const unsigned long long lmask = (1ull << lane) - 1ull;

    float v0[4], v1[4];
    unsigned u0[4], u1[4];
#pragma unroll
    for (int j = 0; j < 4; ++j) {
        v0[j] = s0g[(size_t)r * PKx + lane + 64 * j];
        v1[j] = s1g[(size_t)r * PKx + lane + 64 * j];
        u0[j] = fkey(v0[j]);
        u1[j] = fkey(v1[j]);
    }

    unsigned T0 = 0, T1 = 0;
    for (int bit = 31; bit >= 0; --bit) {
        const unsigned c0 = T0 | (1u << bit);
        const unsigned c1 = T1 | (1u << bit);
        int n0 = 0, n1 = 0;
#pragma unroll
        for (int j = 0; j < 4; ++j) {
            n0 += __popcll(__ballot(u0[j] >= c0));
            n1 += __popcll(__ballot(u1[j] >= c1));
        }
        if (n0 >= Kx) T0 = c0;
        if (n1 >= Kx) T1 = c1;
    }
    extract16(v0, u0, T0, lane, lmask, &sc0[w][0], &ix0[w][0]);
    extract16(v1, u1, T1, lane, lmask, &sc1[w][0], &ix1[w][0]);
    __syncthreads();

    float cv[4];
    unsigned cu[4];
    int ci[4];
#pragma unroll
    for (int j = 0; j < 4; ++j) {
        int p = lane + 64 * j;
        cv[j] = sc0[w][p >> 4] + sc1[w][p & 15];
        cu[j] = fkey(cv[j]);
        ci[j] = ix0[w][p >> 4] + ix1[w][p & 15];  // reference ADDS indices
    }
    unsigned T2 = 0;
    for (int bit = 31; bit >= 0; --bit) {
        const unsigned c2 = T2 | (1u << bit);
        int n2 = 0;
#pragma unroll
        for (int j = 0; j < 4; ++j) n2 += __popcll(__ballot(cu[j] >= c2));
        if (n2 >= Kx) T2 = c2;
    }
    {
        unsigned long long mg[4];
        int gt_total = 0;
#pragma unroll
        for (int j = 0; j < 4; ++j) {
            mg[j] = __ballot(cu[j] > T2);
            gt_total += __popcll(mg[j]);
        }
        int bg = 0, be = gt_total;
#pragma unroll
        for (int j = 0; j < 4; ++j) {
            unsigned long long me = __ballot(cu[j] == T2);
            if (cu[j] > T2) {
                int pg = bg + __popcll(mg[j] & lmask);
                fsv[w][pg] = cv[j]; fid[w][pg] = ci[j];
            } else if (cu[j] == T2) {
                int pe = be + __popcll(me & lmask);
                if (pe < 16) { fsv[w][pe] = cv[j]; fid[w][pe] = ci[j]; }
            }
            bg += __popcll(mg[j]);
            be += __popcll(me);
        }
    }
    __syncthreads();

    float f = fsv[w][lane & 15];
    float mx = f;
#pragma unroll
    for (int off = 8; off; off >>= 1) mx = fmaxf(mx, __shfl_xor(mx, off, 16));
    float e = expf(f - mx);
    float sum = e;
#pragma unroll
    for (int off = 8; off; off >>= 1) sum += __shfl_xor(sum, off, 16);
    if (lane < Kx) {
        fib[(size_t)r * Kx + lane] = fid[w][lane];
        wb[(size_t)r * Kx + lane]  = e / sum;
    }
}

// ---------------------------------------------------------------------------
// K5: expert evaluation with bf16 tables (halved gather traffic).
// One block (4 waves) per s. phase1: lane owns 8 contiguous d-cols; 16B loads.
// phase2: waves split 128 p (32 each), lane owns 8 contiguous out cols.
// ---------------------------------------------------------------------------
__global__ __launch_bounds__(256) void expert_kernel(
    const float* __restrict__ hidden,
    const unsigned short* __restrict__ downb,
    const unsigned short* __restrict__ upb,
    const int* __restrict__ fib,
    const float* __restrict__ wb, float* __restrict__ out)
{
    __shared__ float aw[Hx * Kx];
    __shared__ int fis[Hx * Kx];
    __shared__ float part[4][Ox];
    const int s = blockIdx.x;
    const int tid = threadIdx.x;
    const int wv = tid >> 6;
    const int lane = tid & 63;
    if (tid < Hx * Kx) fis[tid] = fib[(size_t)s * (Hx * Kx) + tid];
    // hidden row: lane owns 8 contiguous cols
    float h8[8];
    {
        float4 a = *(const float4*)&hidden[(size_t)s * Dx + lane * 8];
        float4 b = *(const float4*)&hidden[(size_t)s * Dx + lane * 8 + 4];
        h8[0] = a.x; h8[1] = a.y; h8[2] = a.z; h8[3] = a.w;
        h8[4] = b.x; h8[5] = b.y; h8[6] = b.z; h8[7] = b.w;
    }
    __syncthreads();
    for (int p = wv; p < Hx * Kx; p += 4) {
        const unsigned short* dr = downb + (size_t)fis[p] * Dx + lane * 8;
        int4 d = *(const int4*)dr;   // 8 bf16
        float acc = 0.f;
        acc = fmaf(h8[0], bf2f((unsigned short)(d.x)),       acc);
        acc = fmaf(h8[1], bf2f((unsigned short)(d.x >> 16)), acc);
        acc = fmaf(h8[2], bf2f((unsigned short)(d.y)),       acc);
        acc = fmaf(h8[3], bf2f((unsigned short)(d.y >> 16)), acc);
        acc = fmaf(h8[4], bf2f((unsigned short)(d.z)),       acc);
        acc = fmaf(h8[5], bf2f((unsigned short)(d.z >> 16)), acc);
        acc = fmaf(h8[6], bf2f((unsigned short)(d.w)),       acc);
        acc = fmaf(h8[7], bf2f((unsigned short)(d.w >> 16)), acc);
#pragma unroll
        for (int off = 32; off; off >>= 1) acc += __shfl_xor(acc, off);
        if (lane == 0) {
            float x = acc;
            float act = 0.5f * x * (1.f + erff(x * 0.70710678118654752f));
            aw[p] = act * wb[(size_t)s * (Hx * Kx) + p];
        }
    }
    __syncthreads();
    float a8[8] = {0.f, 0.f, 0.f, 0.f, 0.f, 0.f, 0.f, 0.f};
    const int o0 = lane * 8;
    for (int p = wv * 32; p < wv * 32 + 32; ++p) {
        const float a = aw[p];
        const unsigned short* ur = upb + (size_t)fis[p] * Ox + o0;
        int4 u = *(const int4*)ur;   // 8 bf16
        a8[0] = fmaf(a, bf2f((unsigned short)(u.x)),       a8[0]);
        a8[1] = fmaf(a, bf2f((unsigned short)(u.x >> 16)), a8[1]);
        a8[2] = fmaf(a, bf2f((unsigned short)(u.y)),       a8[2]);
        a8[3] = fmaf(a, bf2f((unsigned short)(u.y >> 16)), a8[3]);
        a8[4] = fmaf(a, bf2f((unsigned short)(u.z)),       a8[4]);
        a8[5] = fmaf(a, bf2f((unsigned short)(u.z >> 16)), a8[5]);
        a8[6] = fmaf(a, bf2f((unsigned short)(u.w)),       a8[6]);
        a8[7] = fmaf(a, bf2f((unsigned short)(u.w >> 16)), a8[7]);
    }
    *(float4*)&part[wv][o0]     = make_float4(a8[0], a8[1], a8[2], a8[3]);
    *(float4*)&part[wv][o0 + 4] = make_float4(a8[4], a8[5], a8[6], a8[7]);
    __syncthreads();
    float r0 = part[0][tid] + part[1][tid] + part[2][tid] + part[3][tid];
    float r1 = part[0][tid + 256] + part[1][tid + 256]
             + part[2][tid + 256] + part[3][tid + 256];
    out[(size_t)s * Ox + tid]       = r0;
    out[(size_t)s * Ox + tid + 256] = r1;
}

// ---------------------------------------------------------------------------
extern "C" void kernel_launch(void* const* d_in, const int* in_sizes, int n_in,
                              void* d_out, int out_size, void* d_ws, size_t ws_size,
                              hipStream_t stream)
{
    const float* hidden = (const float*)d_in[0];
    const float* Wq     = (const float*)d_in[1];
    const float* bq     = (const float*)d_in[2];
    const float* ln_g   = (const float*)d_in[3];
    const float* ln_b   = (const float*)d_in[4];
    const float* keys0  = (const float*)d_in[5];
    const float* keys1  = (const float*)d_in[6];
    const float* edown  = (const float*)d_in[7];
    const float* eup    = (const float*)d_in[8];
    float* out = (float*)d_out;

    // workspace layout
    char* w = (char*)d_ws;
    float* q    = (float*)w;   w += (size_t)Sx * HQx * 4;     // 16 MB
    float* k0n  = (float*)w;   w += (size_t)PKx * HALFx * 4;
    float* k1n  = (float*)w;   w += (size_t)PKx * HALFx * 4;
    float* s0   = (float*)w;   w += (size_t)Rx * PKx * 4;     // 16 MB
    float* s1   = (float*)w;   w += (size_t)Rx * PKx * 4;     // 16 MB
    float* wb   = (float*)w;   w += (size_t)Rx * Kx * 4;
    int*   fib  = (int*)w;     w += (size_t)Rx * Kx * 4;
    unsigned short* downb = (unsigned short*)w; w += (size_t)NEXP * Dx * 2 + 64;
    unsigned short* upb   = (unsigned short*)w; w += (size_t)NEXP * Ox * 2 + 64;

    const int nconv4 = NEXP * Dx / 4;   // 65408 float4 groups per table

    hipLaunchKernelGGL(knorm_kernel, dim3(2 * PKx), dim3(64), 0, stream,
                       keys0, keys1, k0n, k1n);
    hipLaunchKernelGGL(conv_kernel, dim3((nconv4 + 255) / 256), dim3(256), 0, stream,
                       edown, downb, nconv4);
    hipLaunchKernelGGL(conv_kernel, dim3((nconv4 + 255) / 256), dim3(256), 0, stream,
                       eup, upb, nconv4);
    // qproj: q(2048x2048) = hidden @ Wq^T + bq  (f32 — selection path stays exact)
    hipLaunchKernelGGL(gemm128_kernel, dim3(HQx / 64, Sx / 128), dim3(256), 0, stream,
                       hidden, Dx, Wq, Dx, bq, q, HQx, Dx);
    hipLaunchKernelGGL(ln_kernel, dim3(Rx / 4), dim3(256), 0, stream, q, ln_g, ln_b);
    // scores: s_half(16384x256) = qn_half(16384x128) @ keys_half^T  (f32)
    hipLaunchKernelGGL(gemm128_kernel, dim3(PKx / 64, Rx / 128), dim3(256), 0, stream,
                       q, QDx, k0n, HALFx, (const float*)nullptr, s0, PKx, HALFx);
    hipLaunchKernelGGL(gemm128_kernel, dim3(PKx / 64, Rx / 128), dim3(256), 0, stream,
                       q + HALFx, QDx, k1n, HALFx, (const float*)nullptr, s1, PKx, HALFx);
    hipLaunchKernelGGL(topk_kernel, dim3(Rx / 4), dim3(256), 0, stream, s0, s1, fib, wb);
    hipLaunchKernelGGL(expert_kernel, dim3(Sx), dim3(256), 0, stream,
                       hidden, downb, upb, fib, wb, out);
}

// Round 7
// 409.302 us; speedup vs baseline: 1.0494x; 1.0125x over previous
//
#include <hip/hip_runtime.h>
#include <math.h>

// Problem constants (match reference)
constexpr int Sx    = 2048;
constexpr int Dx    = 512;
constexpr int Hx    = 8;
constexpr int QDx   = 256;
constexpr int HALFx = 128;
constexpr int PKx   = 256;
constexpr int Kx    = 16;
constexpr int HQx   = Hx * QDx;   // 2048
constexpr int Rx    = Sx * Hx;    // 16384 (s,h) rows
constexpr int Ox    = 512;
constexpr int NEXP  = 511;        // ci = ix0+ix1 <= 510 -> only rows 0..510 used

// ---- bf16 helpers (RNE) ----------------------------------------------------
__device__ __forceinline__ unsigned short f2bf(float x) {
    unsigned u = __float_as_uint(x);
    unsigned r = (u + 0x7FFFu + ((u >> 16) & 1u)) >> 16;
    return (unsigned short)r;
}
__device__ __forceinline__ float bf2f(unsigned short h) {
    return __uint_as_float(((unsigned)h) << 16);
}

// ---------------------------------------------------------------------------
// K0: l2-normalize the product keys (2 x 256 rows of 128), f32 out.
// ---------------------------------------------------------------------------
__global__ __launch_bounds__(64) void knorm_kernel(
    const float* __restrict__ k0, const float* __restrict__ k1,
    float* __restrict__ k0n, float* __restrict__ k1n)
{
    const int row = blockIdx.x;              // 0..511
    const float* src = (row < PKx) ? (k0 + (size_t)row * HALFx)
                                   : (k1 + (size_t)(row - PKx) * HALFx);
    float* dst = (row < PKx) ? (k0n + (size_t)row * HALFx)
                             : (k1n + (size_t)(row - PKx) * HALFx);
    const int t = threadIdx.x;               // 0..63
    float a = src[t];
    float b = src[t + 64];
    float ss = a * a + b * b;
#pragma unroll
    for (int off = 32; off; off >>= 1) ss += __shfl_xor(ss, off);
    float n = fmaxf(sqrtf(ss), 1e-12f);
    dst[t]      = a / n;
    dst[t + 64] = b / n;
}

// ---------------------------------------------------------------------------
// Kc: convert first NEXP rows of both expert tables to bf16 (one launch).
// n4 = NEXP*Dx/4 groups per table; total 2*n4.
// ---------------------------------------------------------------------------
__global__ __launch_bounds__(256) void conv_kernel(
    const float* __restrict__ down, unsigned short* __restrict__ downb,
    const float* __restrict__ up, unsigned short* __restrict__ upb, int n4)
{
    int i = blockIdx.x * 256 + threadIdx.x;
    if (i >= 2 * n4) return;
    const float* src = (i < n4) ? down : up;
    unsigned short* dst = (i < n4) ? downb : upb;
    int j = (i < n4) ? i : i - n4;
    float4 v = ((const float4*)src)[j];
    ((ushort4*)dst)[j] = make_ushort4(f2bf(v.x), f2bf(v.y), f2bf(v.z), f2bf(v.w));
}

// ---------------------------------------------------------------------------
// K1: f32 GEMM with blockIdx.z job select (split-K or half-select):
//   z: B = z?B1:B0, C = z?C1:C0, A += z*aoff_mult + z*koff_mult, B += z*koff_mult
// BM=128, BN=64, BK=32, 256 threads, per-thread 8x4 tile, reg prefetch.
// qproj:  A=hidden lda=512 aoff=0 koff=256 K=256, B0=B1=Wq, C0/C1 partials.
// scores: A=qn lda=256 aoff=128 koff=0 K=128, B0=k0n B1=k1n, C0=s0 C1=s1.
// ---------------------------------------------------------------------------
__global__ __launch_bounds__(256) void gemm_z_kernel(
    const float* __restrict__ A, int lda, int aoff_mult,
    const float* __restrict__ B0, const float* __restrict__ B1, int ldb,
    float* __restrict__ C0, float* __restrict__ C1, int ldc,
    int K, int koff_mult)
{
    constexpr int BM = 128, BN = 64, BK = 32;
    constexpr int ASTR = BM + 4;   // 132
    constexpr int BSTR = BN + 4;   // 68
    __shared__ __align__(16) float As[BK * ASTR];
    __shared__ __align__(16) float Bs[BK * BSTR];
    const int z = blockIdx.z;
    const float* B = z ? B1 : B0;
    float* C = z ? C1 : C0;
    A += (size_t)z * (aoff_mult + koff_mult);
    B += (size_t)z * koff_mult;

    const int tid = threadIdx.x;
    const int bm = blockIdx.y * BM;
    const int bn = blockIdx.x * BN;

    const int sq = tid & 7;          // k-quad (k = sq*4..sq*4+3)
    const int sr = tid >> 3;         // base row 0..31
    const int m0 = (tid >> 4) * 8;   // 8 rows
    const int n0 = (tid & 15) * 4;   // 4 cols

    float4 pa[4], pb[2];
#pragma unroll
    for (int i = 0; i < 4; ++i)
        pa[i] = *(const float4*)&A[(size_t)(bm + sr + i * 32) * lda + sq * 4];
#pragma unroll
    for (int i = 0; i < 2; ++i)
        pb[i] = *(const float4*)&B[(size_t)(bn + sr + i * 32) * ldb + sq * 4];

    float acc[8][4] = {{0.f}};
    const int niter = K / BK;
    for (int it = 0; it < niter; ++it) {
        __syncthreads();
#pragma unroll
        for (int i = 0; i < 4; ++i) {
            const float v[4] = {pa[i].x, pa[i].y, pa[i].z, pa[i].w};
#pragma unroll
            for (int j = 0; j < 4; ++j)
                As[(sq * 4 + j) * ASTR + sr + i * 32] = v[j];
        }
#pragma unroll
        for (int i = 0; i < 2; ++i) {
            const float v[4] = {pb[i].x, pb[i].y, pb[i].z, pb[i].w};
#pragma unroll
            for (int j = 0; j < 4; ++j)
                Bs[(sq * 4 + j) * BSTR + sr + i * 32] = v[j];
        }
        __syncthreads();
        if (it + 1 < niter) {
            const int ko = (it + 1) * BK;
#pragma unroll
            for (int i = 0; i < 4; ++i)
                pa[i] = *(const float4*)&A[(size_t)(bm + sr + i * 32) * lda + ko + sq * 4];
#pragma unroll
            for (int i = 0; i < 2; ++i)
                pb[i] = *(const float4*)&B[(size_t)(bn + sr + i * 32) * ldb + ko + sq * 4];
        }
#pragma unroll
        for (int k = 0; k < BK; ++k) {
            float af[8], bf[4];
            *(float4*)&af[0] = *(const float4*)&As[k * ASTR + m0];
            *(float4*)&af[4] = *(const float4*)&As[k * ASTR + m0 + 4];
            *(float4*)&bf[0] = *(const float4*)&Bs[k * BSTR + n0];
#pragma unroll
            for (int i = 0; i < 8; ++i)
#pragma unroll
                for (int j = 0; j < 4; ++j)
                    acc[i][j] = fmaf(af[i], bf[j], acc[i][j]);
        }
    }
#pragma unroll
    for (int i = 0; i < 8; ++i) {
        float4 o = make_float4(acc[i][0], acc[i][1], acc[i][2], acc[i][3]);
        *(float4*)&C[(size_t)(bm + m0 + i) * ldc + bn + n0] = o;
    }
}

// ---------------------------------------------------------------------------
// K2: sum split-K partials + bias + LayerNorm(256) + split-half l2norm.
// Writes normalized q to qn. 4 rows per 256-thread block.
// q element (s, h*256+qd) has flat index r*256+qd where r = s*8+h.
// ---------------------------------------------------------------------------
__global__ __launch_bounds__(256) void ln_kernel(
    const float* __restrict__ q0, const float* __restrict__ q1,
    const float* __restrict__ bq,
    const float* __restrict__ g, const float* __restrict__ b,
    float* __restrict__ qn)
{
    const int r = blockIdx.x * 4 + (threadIdx.x >> 6);   // 0..16383
    const float* row0 = q0 + (size_t)r * QDx;
    const float* row1 = q1 + (size_t)r * QDx;
    const int t = threadIdx.x & 63;
    const int cb = (r & 7) * QDx;    // bias column base = h*256
    float v0 = row0[t]       + row1[t]       + bq[cb + t];
    float v1 = row0[t + 64]  + row1[t + 64]  + bq[cb + t + 64];
    float v2 = row0[t + 128] + row1[t + 128] + bq[cb + t + 128];
    float v3 = row0[t + 192] + row1[t + 192] + bq[cb + t + 192];
    float sum = v0 + v1 + v2 + v3;
#pragma unroll
    for (int off = 32; off; off >>= 1) sum += __shfl_xor(sum, off);
    const float mu = sum * (1.f / 256.f);
    float d0 = v0 - mu, d1 = v1 - mu, d2 = v2 - mu, d3 = v3 - mu;
    float ss = d0 * d0 + d1 * d1 + d2 * d2 + d3 * d3;
#pragma unroll
    for (int off = 32; off; off >>= 1) ss += __shfl_xor(ss, off);
    const float var = ss * (1.f / 256.f);
    const float inv = 1.0f / sqrtf(var + 1e-5f);
    v0 = d0 * inv * g[t]       + b[t];
    v1 = d1 * inv * g[t + 64]  + b[t + 64];
    v2 = d2 * inv * g[t + 128] + b[t + 128];
    v3 = d3 * inv * g[t + 192] + b[t + 192];
    float s0 = v0 * v0 + v1 * v1;
#pragma unroll
    for (int off = 32; off; off >>= 1) s0 += __shfl_xor(s0, off);
    float n0 = fmaxf(sqrtf(s0), 1e-12f);
    float s1 = v2 * v2 + v3 * v3;
#pragma unroll
    for (int off = 32; off; off >>= 1) s1 += __shfl_xor(s1, off);
    float n1 = fmaxf(sqrtf(s1), 1e-12f);
    float* row = qn + (size_t)r * QDx;
    row[t]       = v0 / n0;
    row[t + 64]  = v1 / n0;
    row[t + 128] = v2 / n1;
    row[t + 192] = v3 / n1;
}

// ---------------------------------------------------------------------------
// K4: per (s,h) row top-16 x3 + softmax. Ballot radix select.
// 4 rows per 256-thread block (one row per wave).
// ---------------------------------------------------------------------------
__device__ __forceinline__ unsigned fkey(float f) {
    unsigned u = __float_as_uint(f);
    return u ^ ((u & 0x80000000u) ? 0xFFFFFFFFu : 0x80000000u);
}

__device__ __forceinline__ void extract16(
    const float v[4], const unsigned u[4], unsigned T, int lane,
    unsigned long long lmask, float* outv, int* outi)
{
    unsigned long long mg[4];
    int gt_total = 0;
#pragma unroll
    for (int j = 0; j < 4; ++j) {
        mg[j] = __ballot(u[j] > T);
        gt_total += __popcll(mg[j]);
    }
    int bg = 0, be = gt_total;
#pragma unroll
    for (int j = 0; j < 4; ++j) {
        unsigned long long me = __ballot(u[j] == T);
        int idx = lane + 64 * j;
        if (u[j] > T) {
            int pg = bg + __popcll(mg[j] & lmask);
            outv[pg] = v[j]; outi[pg] = idx;
        } else if (u[j] == T) {
            int pe = be + __popcll(me & lmask);
            if (pe < 16) { outv[pe] = v[j]; outi[pe] = idx; }
        }
        bg += __popcll(mg[j]);
        be += __popcll(me);
    }
}

__global__ __launch_bounds__(256) void topk_kernel(
    const float* __restrict__ s0g, const float* __restrict__ s1g,
    int* __restrict__ fib, float* __restrict__ wb)
{
    __shared__ float sc0[4][Kx], sc1[4][Kx], fsv[4][Kx];
    __shared__ int ix0[4][Kx], ix1[4][Kx], fid[4][Kx];
    const int w = threadIdx.x >> 6;
    const int r = blockIdx.x * 4 + w;
    const int lane = threadIdx.x & 63;
    const unsigned long long lmask = (1ull << lane) - 1ull;

    float v0[4], v1[4];
    unsigned u0[4], u1[4];
#pragma unroll
    for (int j = 0; j < 4; ++j) {
        v0[j] = s0g[(size_t)r * PKx + lane + 64 * j];
        v1[j] = s1g[(size_t)r * PKx + lane + 64 * j];
        u0[j] = fkey(v0[j]);
        u1[j] = fkey(v1[j]);
    }

    unsigned T0 = 0, T1 = 0;
    for (int bit = 31; bit >= 0; --bit) {
        const unsigned c0 = T0 | (1u << bit);
        const unsigned c1 = T1 | (1u << bit);
        int n0 = 0, n1 = 0;
#pragma unroll
        for (int j = 0; j < 4; ++j) {
            n0 += __popcll(__ballot(u0[j] >= c0));
            n1 += __popcll(__ballot(u1[j] >= c1));
        }
        if (n0 >= Kx) T0 = c0;
        if (n1 >= Kx) T1 = c1;
    }
    extract16(v0, u0, T0, lane, lmask, &sc0[w][0], &ix0[w][0]);
    extract16(v1, u1, T1, lane, lmask, &sc1[w][0], &ix1[w][0]);
    __syncthreads();

    float cv[4];
    unsigned cu[4];
    int ci[4];
#pragma unroll
    for (int j = 0; j < 4; ++j) {
        int p = lane + 64 * j;
        cv[j] = sc0[w][p >> 4] + sc1[w][p & 15];
        cu[j] = fkey(cv[j]);
        ci[j] = ix0[w][p >> 4] + ix1[w][p & 15];  // reference ADDS indices
    }
    unsigned T2 = 0;
    for (int bit = 31; bit >= 0; --bit) {
        const unsigned c2 = T2 | (1u << bit);
        int n2 = 0;
#pragma unroll
        for (int j = 0; j < 4; ++j) n2 += __popcll(__ballot(cu[j] >= c2));
        if (n2 >= Kx) T2 = c2;
    }
    {
        unsigned long long mg[4];
        int gt_total = 0;
#pragma unroll
        for (int j = 0; j < 4; ++j) {
            mg[j] = __ballot(cu[j] > T2);
            gt_total += __popcll(mg[j]);
        }
        int bg = 0, be = gt_total;
#pragma unroll
        for (int j = 0; j < 4; ++j) {
            unsigned long long me = __ballot(cu[j] == T2);
            if (cu[j] > T2) {
                int pg = bg + __popcll(mg[j] & lmask);
                fsv[w][pg] = cv[j]; fid[w][pg] = ci[j];
            } else if (cu[j] == T2) {
                int pe = be + __popcll(me & lmask);
                if (pe < 16) { fsv[w][pe] = cv[j]; fid[w][pe] = ci[j]; }
            }
            bg += __popcll(mg[j]);
            be += __popcll(me);
        }
    }
    __syncthreads();

    float f = fsv[w][lane & 15];
    float mx = f;
#pragma unroll
    for (int off = 8; off; off >>= 1) mx = fmaxf(mx, __shfl_xor(mx, off, 16));
    float e = expf(f - mx);
    float sum = e;
#pragma unroll
    for (int off = 8; off; off >>= 1) sum += __shfl_xor(sum, off, 16);
    if (lane < Kx) {
        fib[(size_t)r * Kx + lane] = fid[w][lane];
        wb[(size_t)r * Kx + lane]  = e / sum;
    }
}

// ---------------------------------------------------------------------------
// K5: expert evaluation, bf16 tables. One block (4 waves) per s.
// phase1: 8 lanes per expert dot (sub = lane&7 owns a 64-col chunk of the
//   512-dot; hidden row in bank-padded LDS), 3 shuffle levels x 4 iters
//   per wave (was 6 x 32 -> DS-pipe chain eliminated).
// phase2: waves split 128 p (32 each), lane owns 8 contiguous out cols.
// ---------------------------------------------------------------------------
__global__ __launch_bounds__(256) void expert_kernel(
    const float* __restrict__ hidden,
    const unsigned short* __restrict__ downb,
    const unsigned short* __restrict__ upb,
    const int* __restrict__ fib,
    const float* __restrict__ wb, float* __restrict__ out)
{
    __shared__ float hsp[8 * 68];      // col c -> (c>>6)*68 + (c&63), pad-8 banks
    __shared__ float aw[Hx * Kx];
    __shared__ int fis[Hx * Kx];
    __shared__ float part[4][Ox];
    const int s = blockIdx.x;
    const int tid = threadIdx.x;
    const int wv = tid >> 6;
    const int lane = tid & 63;
    if (tid < Hx * Kx) fis[tid] = fib[(size_t)s * (Hx * Kx) + tid];
#pragma unroll
    for (int c = tid; c < Dx; c += 256)
        hsp[(c >> 6) * 68 + (c & 63)] = hidden[(size_t)s * Dx + c];
    __syncthreads();

    const int sub = lane & 7;          // column-chunk owner
    const int pl  = lane >> 3;         // p within 8-group
    const float* hc = &hsp[sub * 68];
    for (int pb = wv * 32; pb < wv * 32 + 32; pb += 8) {
        const int p = pb + pl;
        const unsigned short* dr = downb + (size_t)fis[p] * Dx + sub * 64;
        float acc = 0.f;
#pragma unroll
        for (int j = 0; j < 8; ++j) {
            int4 d = *(const int4*)(dr + j * 8);
            float4 ha = *(const float4*)&hc[j * 8];
            float4 hb = *(const float4*)&hc[j * 8 + 4];
            acc = fmaf(ha.x, bf2f((unsigned short)(d.x)),       acc);
            acc = fmaf(ha.y, bf2f((unsigned short)(d.x >> 16)), acc);
            acc = fmaf(ha.z, bf2f((unsigned short)(d.y)),       acc);
            acc = fmaf(ha.w, bf2f((unsigned short)(d.y >> 16)), acc);
            acc = fmaf(hb.x, bf2f((unsigned short)(d.z)),       acc);
            acc = fmaf(hb.y, bf2f((unsigned short)(d.z >> 16)), acc);
            acc = fmaf(hb.z, bf2f((unsigned short)(d.w)),       acc);
            acc = fmaf(hb.w, bf2f((unsigned short)(d.w >> 16)), acc);
        }
        acc += __shfl_xor(acc, 1);
        acc += __shfl_xor(acc, 2);
        acc += __shfl_xor(acc, 4);
        if (sub == 0) {
            float x = acc;
            float act = 0.5f * x * (1.f + erff(x * 0.70710678118654752f));
            aw[p] = act * wb[(size_t)s * (Hx * Kx) + p];
        }
    }
    __syncthreads();

    float a8[8] = {0.f, 0.f, 0.f, 0.f, 0.f, 0.f, 0.f, 0.f};
    const int o0 = lane * 8;
    for (int p = wv * 32; p < wv * 32 + 32; ++p) {
        const float a = aw[p];
        const unsigned short* ur = upb + (size_t)fis[p] * Ox + o0;
        int4 u = *(const int4*)ur;   // 8 bf16
        a8[0] = fmaf(a, bf2f((unsigned short)(u.x)),       a8[0]);
        a8[1] = fmaf(a, bf2f((unsigned short)(u.x >> 16)), a8[1]);
        a8[2] = fmaf(a, bf2f((unsigned short)(u.y)),       a8[2]);
        a8[3] = fmaf(a, bf2f((unsigned short)(u.y >> 16)), a8[3]);
        a8[4] = fmaf(a, bf2f((unsigned short)(u.z)),       a8[4]);
        a8[5] = fmaf(a, bf2f((unsigned short)(u.z >> 16)), a8[5]);
        a8[6] = fmaf(a, bf2f((unsigned short)(u.w)),       a8[6]);
        a8[7] = fmaf(a, bf2f((unsigned short)(u.w >> 16)), a8[7]);
    }
    *(float4*)&part[wv][o0]     = make_float4(a8[0], a8[1], a8[2], a8[3]);
    *(float4*)&part[wv][o0 + 4] = make_float4(a8[4], a8[5], a8[6], a8[7]);
    __syncthreads();
    float r0 = part[0][tid] + part[1][tid] + part[2][tid] + part[3][tid];
    float r1 = part[0][tid + 256] + part[1][tid + 256]
             + part[2][tid + 256] + part[3][tid + 256];
    out[(size_t)s * Ox + tid]       = r0;
    out[(size_t)s * Ox + tid + 256] = r1;
}

// ---------------------------------------------------------------------------
extern "C" void kernel_launch(void* const* d_in, const int* in_sizes, int n_in,
                              void* d_out, int out_size, void* d_ws, size_t ws_size,
                              hipStream_t stream)
{
    const float* hidden = (const float*)d_in[0];
    const float* Wq     = (const float*)d_in[1];
    const float* bq     = (const float*)d_in[2];
    const float* ln_g   = (const float*)d_in[3];
    const float* ln_b   = (const float*)d_in[4];
    const float* keys0  = (const float*)d_in[5];
    const float* keys1  = (const float*)d_in[6];
    const float* edown  = (const float*)d_in[7];
    const float* eup    = (const float*)d_in[8];
    float* out = (float*)d_out;

    // workspace layout (~84 MB)
    char* w = (char*)d_ws;
    float* q0   = (float*)w;   w += (size_t)Sx * HQx * 4;     // 16 MB
    float* q1   = (float*)w;   w += (size_t)Sx * HQx * 4;     // 16 MB
    float* qn   = (float*)w;   w += (size_t)Sx * HQx * 4;     // 16 MB
    float* k0n  = (float*)w;   w += (size_t)PKx * HALFx * 4;
    float* k1n  = (float*)w;   w += (size_t)PKx * HALFx * 4;
    float* s0   = (float*)w;   w += (size_t)Rx * PKx * 4;     // 16 MB
    float* s1   = (float*)w;   w += (size_t)Rx * PKx * 4;     // 16 MB
    float* wb   = (float*)w;   w += (size_t)Rx * Kx * 4;
    int*   fib  = (int*)w;     w += (size_t)Rx * Kx * 4;
    unsigned short* downb = (unsigned short*)w; w += (size_t)NEXP * Dx * 2 + 64;
    unsigned short* upb   = (unsigned short*)w; w += (size_t)NEXP * Ox * 2 + 64;

    const int nconv4 = NEXP * Dx / 4;   // 65408 float4 groups per table

    hipLaunchKernelGGL(knorm_kernel, dim3(2 * PKx), dim3(64), 0, stream,
                       keys0, keys1, k0n, k1n);
    hipLaunchKernelGGL(conv_kernel, dim3((2 * nconv4 + 255) / 256), dim3(256), 0, stream,
                       edown, downb, eup, upb, nconv4);
    // qproj split-K x2: q0 = hidden[:, :256] @ Wq[:, :256]^T ; q1 = cols 256..511
    hipLaunchKernelGGL(gemm_z_kernel, dim3(HQx / 64, Sx / 128, 2), dim3(256), 0, stream,
                       hidden, Dx, 0, Wq, Wq, Dx, q0, q1, HQx, Dx / 2, Dx / 2);
    // LN: sum partials + bias, normalize, l2norm halves -> qn
    hipLaunchKernelGGL(ln_kernel, dim3(Rx / 4), dim3(256), 0, stream,
                       q0, q1, bq, ln_g, ln_b, qn);
    // scores both halves in one launch: z=0 -> s0 (qn cols 0..127 vs k0n),
    //                                   z=1 -> s1 (qn cols 128..255 vs k1n)
    hipLaunchKernelGGL(gemm_z_kernel, dim3(PKx / 64, Rx / 128, 2), dim3(256), 0, stream,
                       qn, QDx, HALFx, k0n, k1n, HALFx, s0, s1, PKx, HALFx, 0);
    hipLaunchKernelGGL(topk_kernel, dim3(Rx / 4), dim3(256), 0, stream, s0, s1, fib, wb);
    hipLaunchKernelGGL(expert_kernel, dim3(Sx), dim3(256), 0, stream,
                       hidden, downb, upb, fib, wb, out);
}